// Round 5
// baseline (234.515 us; speedup 1.0000x reference)
//
#include <hip/hip_runtime.h>
#include <hip/hip_bf16.h>
#include <hip/hip_fp16.h>

// DCNv2 fused, v4: NHWC bf16 texture + tap-inner K-order + coalesced gathers
// + A-fragments direct from global (no weight LDS) + packed params
// => LDS 46.6KB => 2 blocks/CU at launch_bounds(512,4).
// B=8 C=256 H=W=64 O=256 3x3 s1 p1 d1 DG=1.
// kappa = s*64 + t, s = cblk*9 + k (tap-inner); per b: out = W' @ colsT^T.

typedef unsigned int u32;
typedef unsigned short u16;
typedef __bf16 bf16x8 __attribute__((ext_vector_type(8)));
typedef float f32x4 __attribute__((ext_vector_type(4)));

#define NSP   4096
#define KTOT  2304
#define NSTEP 36

__device__ __forceinline__ u32 f2bf(float f) {  // RNE f32->bf16 (finite data)
  u32 u = __float_as_uint(f);
  return (u + 0x7fffu + ((u >> 16) & 1u)) >> 16;
}
__device__ __forceinline__ u32 pk2(float a, float b) { return f2bf(a) | (f2bf(b) << 16); }
__device__ __forceinline__ float lo16(u32 u) { return __uint_as_float(u << 16); }
__device__ __forceinline__ float hi16(u32 u) { return __uint_as_float(u & 0xffff0000u); }

// NCHW f32 -> NHWC bf16 transpose: Dc[b][y][x][c] = bf16(in[b][c][y][x])
__global__ void prep_input(const float* __restrict__ in, u16* __restrict__ Dc) {
  __shared__ u32 T[64][129];
  int b = blockIdx.x >> 6, y = blockIdx.x & 63;
  const float* src = in + (size_t)b * 1048576 + y * 64;
  int x = threadIdx.x & 63, co = threadIdx.x >> 6;
#pragma unroll 4
  for (int r = 0; r < 32; ++r) {
    int cp = r * 4 + co;
    float v0 = src[(2 * cp) * NSP + x];
    float v1 = src[(2 * cp + 1) * NSP + x];
    T[x][cp] = pk2(v0, v1);
  }
  __syncthreads();
  u16* dst = Dc + (size_t)(b * 64 + y) * 16384;
#pragma unroll
  for (int p = 0; p < 8; ++p) {
    int t = p * 256 + threadIdx.x;          // 16B quad index
    int xx = t >> 5, cp0 = (t & 31) << 2;
    uint4 v;
    v.x = T[xx][cp0]; v.y = T[xx][cp0 + 1]; v.z = T[xx][cp0 + 2]; v.w = T[xx][cp0 + 3];
    *(uint4*)((char*)dst + (size_t)t * 16) = v;
  }
}

// Step-contiguous weight slab: Wp2[(s*256 + o)*64 + t] = bf16(w[o][cblk*64+t][k]),
// s = cblk*9 + k. Each step's 32KB of weights is one contiguous region.
__global__ void prep_weight(const float* __restrict__ w, u16* __restrict__ Wp) {
  int idx = blockIdx.x * 256 + threadIdx.x;   // < 589824
  int s = idx >> 14;
  int r = idx & 16383;
  int o = r >> 6, t = r & 63;
  int cblk = s / 9, k = s - cblk * 9;
  Wp[idx] = (u16)f2bf(w[o * KTOT + (cblk * 64 + t) * 9 + k]);
}

__global__ __launch_bounds__(512, 4) void dcn_main(
    const u16* __restrict__ Dc, const u16* __restrict__ Wp,
    const float* __restrict__ off, const float* __restrict__ msk,
    const float* __restrict__ bias, float* __restrict__ out)
{
  __shared__ u16 ct[2][8192];        // colsT tile, round-3 swizzle (32 KiB)
  __shared__ u32 pPk[9 * 128];       // oA | oB<<16                 (4.5 KiB)
  __shared__ __half2 pW01[9 * 128];  // corner weights (w00,w01)    (4.5 KiB)
  __shared__ __half2 pW23[9 * 128];  // corner weights (w10,w11)    (4.5 KiB)

  const int tid = threadIdx.x;
  const int bid = blockIdx.x;
  const int b  = bid & 7;            // XCD grouping: each XCD -> one batch
  const int n0 = (bid >> 3) << 7;

  // ---------- per-(k, n) bilinear params (verified math, packed stores) ----------
  for (int idx = tid; idx < 9 * 128; idx += 512) {
    int k = idx >> 7, nl = idx & 127;
    int n = n0 + nl;
    int h = n >> 6, w = n & 63;
    int ki = k / 3, kj = k - ki * 3;
    float offy = off[(b * 18 + 2 * k) * NSP + n];
    float offx = off[(b * 18 + 2 * k + 1) * NSP + n];
    float mval = msk[(b * 9 + k) * NSP + n];
    float py = (float)(h - 1 + ki) + offy;
    float px = (float)(w - 1 + kj) + offx;
    float y0f = floorf(py), x0f = floorf(px);
    float ly = py - y0f, lx = px - x0f;
    int y0 = (int)y0f, x0 = (int)x0f;
    int xl = min(max(x0, 0), 62);           // pair (xl, xl+1) stays in row
    float ws0 = 0.f, ws1 = 0.f;
    if (x0 >= 0 && x0 <= 63)         { if (x0 == xl)     ws0 += 1.f - lx; else ws1 += 1.f - lx; }
    if (x0 + 1 >= 0 && x0 + 1 <= 63) { if (x0 + 1 == xl) ws0 += lx;       else ws1 += lx; }
    float wy0 = 1.f - ly, wy1 = ly;
    int oA = 0, oB = 0;
    if (y0 >= 0 && y0 < 64) oA = (y0 << 6) + xl; else wy0 = 0.f;
    if (y0 + 1 >= 0 && y0 + 1 < 64) oB = ((y0 + 1) << 6) + xl; else wy1 = 0.f;
    pPk[idx] = (u32)oA | ((u32)oB << 16);
    pW01[idx] = __floats2half2_rn(wy0 * ws0 * mval, wy0 * ws1 * mval);
    pW23[idx] = __floats2half2_rn(wy1 * ws0 * mval, wy1 * ws1 * mval);
  }
  __syncthreads();

  const char* Db = (const char*)Dc + (size_t)b * 2097152;  // NHWC plane of batch b
  const int wv  = tid >> 6, lane = tid & 63;
  const int wm  = wv & 3,  wn   = wv >> 2;
  const int lr  = lane & 15, lg = lane >> 4;

  uint4 gA0[2], gA1[2], gB0[2], gB1[2];   // corner gathers (round-3 coalesced map)
  f32x4 acc[4][4] = {};

  auto issueG = [&](int s) {              // corner loads for step s
    int cblk = s / 9;
    int k = s - cblk * 9;
    u32 cb2 = (u32)(cblk << 7);
#pragma unroll
    for (int u = 0; u < 2; ++u) {
      int tup = (u << 9) + tid;
      int nl2 = tup >> 3, c8 = tup & 7;   // 8 lanes share one n -> 128B segments
      u32 pk = pPk[(k << 7) + nl2];
      u32 ba = (pk & 0xffffu) * 512u + cb2 + (u32)(c8 << 4);
      u32 bb = (pk >> 16) * 512u + cb2 + (u32)(c8 << 4);
      gA0[u] = *(const uint4*)(Db + ba);          // (y0, xl)
      gA1[u] = *(const uint4*)(Db + ba + 512);    // (y0, xl+1)
      gB0[u] = *(const uint4*)(Db + bb);          // (y1, xl)
      gB1[u] = *(const uint4*)(Db + bb + 512);    // (y1, xl+1)
    }
  };

  auto commitG = [&](int s, u16* ctb) {   // blend + swizzled LDS writes
    int k = s - (s / 9) * 9;
#pragma unroll
    for (int u = 0; u < 2; ++u) {
      int tup = (u << 9) + tid;
      int nl2 = tup >> 3, c8 = tup & 7;
      int pi = (k << 7) + nl2;
      __half2 h01 = pW01[pi], h23 = pW23[pi];
      float s0 = __half2float(h01.x), s1 = __half2float(h01.y);
      float s2 = __half2float(h23.x), s3 = __half2float(h23.y);
      u32 o4[4];
      const u32* a0p = (const u32*)&gA0[u];
      const u32* a1p = (const u32*)&gA1[u];
      const u32* b0p = (const u32*)&gB0[u];
      const u32* b1p = (const u32*)&gB1[u];
#pragma unroll
      for (int j = 0; j < 4; ++j) {
        u32 a0 = a0p[j], a1 = a1p[j], b0 = b0p[j], b1 = b1p[j];
        float vlo = s0 * lo16(a0) + s1 * lo16(a1) + s2 * lo16(b0) + s3 * hi16(b0) * 0.f
                  + s3 * lo16(b1);                 // (expanded below correctly)
        // NOTE: written explicitly to avoid typo risk:
        vlo = s0 * lo16(a0) + s1 * lo16(a1) + s2 * lo16(b0) + s3 * lo16(b1);
        float vhi = s0 * hi16(a0) + s1 * hi16(a1) + s2 * hi16(b0) + s3 * hi16(b1);
        o4[j] = pk2(vlo, vhi);
      }
      int byteoff = nl2 * 128 + ((c8 ^ (nl2 & 7)) << 4);
      *(uint4*)((char*)ctb + byteoff) = make_uint4(o4[0], o4[1], o4[2], o4[3]);
    }
  };

  // ---------- main K loop (ct double-buffered, A direct from global) ----------
  issueG(0);
  commitG(0, ct[0]);
  __syncthreads();
  int cur = 0;
  for (int s = 0; s < NSTEP; ++s) {
    int nx = cur ^ 1;
    const char* slab = (const char*)Wp + (size_t)s * 32768;
    // A-fragment loads for this step (issued first so MFMA's vmcnt wait
    // does not force next-step gathers to retire)
    uint4 af[2][4];
#pragma unroll
    for (int kh = 0; kh < 2; ++kh)
#pragma unroll
      for (int fm = 0; fm < 4; ++fm) {
        int o = (wm << 6) + (fm << 4) + lr;
        af[kh][fm] = *(const uint4*)(slab + o * 128 + (kh << 6) + (lg << 4));
      }
    if (s + 1 < NSTEP) issueG(s + 1);     // gathers in flight during MFMA
    const u16* ctb = ct[cur];
#pragma unroll
    for (int kh = 0; kh < 2; ++kh) {
      int c16 = (kh << 2) + lg;
      bf16x8 bfr[4];
#pragma unroll
      for (int fn = 0; fn < 4; ++fn) {
        int nrow = (wn << 6) + (fn << 4) + lr;
        bfr[fn] = *(const bf16x8*)((const char*)ctb + nrow * 128 + ((c16 ^ (nrow & 7)) << 4));
      }
#pragma unroll
      for (int fm = 0; fm < 4; ++fm) {
        bf16x8 a8 = *(const bf16x8*)&af[kh][fm];
#pragma unroll
        for (int fn = 0; fn < 4; ++fn)
          acc[fm][fn] = __builtin_amdgcn_mfma_f32_16x16x32_bf16(a8, bfr[fn], acc[fm][fn], 0, 0, 0);
      }
    }
    if (s + 1 < NSTEP) commitG(s + 1, ct[nx]);
    __syncthreads();
    cur = nx;
  }

  // ---------- epilogue ----------
#pragma unroll
  for (int fm = 0; fm < 4; ++fm) {
    int mb = (wm << 6) + (fm << 4) + (lg << 2);
#pragma unroll
    for (int r = 0; r < 4; ++r) {
      int m = mb + r;
      float bv = bias[m];
      int obase = (((b << 8) + m) << 12) + n0 + (wn << 6) + lr;
#pragma unroll
      for (int fn = 0; fn < 4; ++fn)
        out[obase + (fn << 4)] = acc[fm][fn][r] + bv;
    }
  }
}

extern "C" void kernel_launch(void* const* d_in, const int* in_sizes, int n_in,
                              void* d_out, int out_size, void* d_ws, size_t ws_size,
                              hipStream_t stream) {
  const float* inp  = (const float*)d_in[0];
  const float* off  = (const float*)d_in[1];
  const float* msk  = (const float*)d_in[2];
  const float* wgt  = (const float*)d_in[3];
  const float* bias = (const float*)d_in[4];
  float* out = (float*)d_out;

  u16* Dc = (u16*)d_ws;                                    // 16,777,216 B
  u16* Wp = (u16*)((char*)d_ws + (size_t)16777216);        //  1,179,648 B

  prep_input<<<512, 256, 0, stream>>>(inp, Dc);
  prep_weight<<<(589824) / 256, 256, 0, stream>>>(wgt, Wp);
  dcn_main<<<256, 512, 0, stream>>>(Dc, Wp, off, msk, bias, out);
}

// Round 6
// 198.788 us; speedup vs baseline: 1.1797x; 1.1797x over previous
//
#include <hip/hip_runtime.h>
#include <hip/hip_bf16.h>
#include <hip/hip_fp16.h>

// DCNv2 fused, v5: round-5 structure (NHWC bf16 texture, tap-inner K-order,
// coalesced gathers, A-fragments direct from global, packed params, swizzled
// ct) with the spill fixed: launch_bounds(512,2) => VGPR cap 256.
// B=8 C=256 H=W=64 O=256 3x3 s1 p1 d1 DG=1.
// kappa = s*64 + t, s = cblk*9 + k (tap-inner); per b: out = W' @ colsT^T.

typedef unsigned int u32;
typedef unsigned short u16;
typedef __bf16 bf16x8 __attribute__((ext_vector_type(8)));
typedef float f32x4 __attribute__((ext_vector_type(4)));

#define NSP   4096
#define KTOT  2304
#define NSTEP 36

__device__ __forceinline__ u32 f2bf(float f) {  // RNE f32->bf16 (finite data)
  u32 u = __float_as_uint(f);
  return (u + 0x7fffu + ((u >> 16) & 1u)) >> 16;
}
__device__ __forceinline__ u32 pk2(float a, float b) { return f2bf(a) | (f2bf(b) << 16); }
__device__ __forceinline__ float lo16(u32 u) { return __uint_as_float(u << 16); }
__device__ __forceinline__ float hi16(u32 u) { return __uint_as_float(u & 0xffff0000u); }

// One dispatch for both preps.
// blocks [0,512): NCHW f32 -> NHWC bf16: Dc[b][y][x][c] = bf16(in[b][c][y][x])
// blocks [512, 512+2304): step-contiguous weight slab:
//   Wp[(s*256 + o)*64 + t] = bf16(w[o][cblk*64+t][k]), s = cblk*9+k.
__global__ void prep_all(const float* __restrict__ in, const float* __restrict__ w,
                         u16* __restrict__ Dc, u16* __restrict__ Wp) {
  __shared__ u32 T[64][129];
  if (blockIdx.x < 512) {
    int b = blockIdx.x >> 6, y = blockIdx.x & 63;
    const float* src = in + (size_t)b * 1048576 + y * 64;
    int x = threadIdx.x & 63, co = threadIdx.x >> 6;
#pragma unroll 8
    for (int r = 0; r < 32; ++r) {
      int cp = r * 4 + co;
      float v0 = src[(2 * cp) * NSP + x];
      float v1 = src[(2 * cp + 1) * NSP + x];
      T[x][cp] = pk2(v0, v1);
    }
    __syncthreads();
    u16* dst = Dc + (size_t)(b * 64 + y) * 16384;
#pragma unroll
    for (int p = 0; p < 8; ++p) {
      int t = p * 256 + threadIdx.x;          // 16B quad index
      int xx = t >> 5, cp0 = (t & 31) << 2;
      uint4 v;
      v.x = T[xx][cp0]; v.y = T[xx][cp0 + 1]; v.z = T[xx][cp0 + 2]; v.w = T[xx][cp0 + 3];
      *(uint4*)((char*)dst + (size_t)t * 16) = v;
    }
  } else {
    int idx = (blockIdx.x - 512) * 256 + threadIdx.x;   // < 589824
    int s = idx >> 14;
    int r = idx & 16383;
    int o = r >> 6, t = r & 63;
    int cblk = s / 9, k = s - cblk * 9;
    Wp[idx] = (u16)f2bf(w[o * KTOT + (cblk * 64 + t) * 9 + k]);
  }
}

__global__ __launch_bounds__(512, 2) void dcn_main(
    const u16* __restrict__ Dc, const u16* __restrict__ Wp,
    const float* __restrict__ off, const float* __restrict__ msk,
    const float* __restrict__ bias, float* __restrict__ out)
{
  __shared__ u16 ct[2][8192];        // colsT tile, swizzled        (32 KiB)
  __shared__ u32 pPk[9 * 128];       // oA | oB<<16                 (4.5 KiB)
  __shared__ __half2 pW01[9 * 128];  // corner weights (w00,w01)    (4.5 KiB)
  __shared__ __half2 pW23[9 * 128];  // corner weights (w10,w11)    (4.5 KiB)

  const int tid = threadIdx.x;
  const int bid = blockIdx.x;
  const int b  = bid & 7;            // XCD grouping: each XCD -> one batch
  const int n0 = (bid >> 3) << 7;

  // ---------- per-(k, n) bilinear params (verified math) ----------
  for (int idx = tid; idx < 9 * 128; idx += 512) {
    int k = idx >> 7, nl = idx & 127;
    int n = n0 + nl;
    int h = n >> 6, w = n & 63;
    int ki = k / 3, kj = k - ki * 3;
    float offy = off[(b * 18 + 2 * k) * NSP + n];
    float offx = off[(b * 18 + 2 * k + 1) * NSP + n];
    float mval = msk[(b * 9 + k) * NSP + n];
    float py = (float)(h - 1 + ki) + offy;
    float px = (float)(w - 1 + kj) + offx;
    float y0f = floorf(py), x0f = floorf(px);
    float ly = py - y0f, lx = px - x0f;
    int y0 = (int)y0f, x0 = (int)x0f;
    int xl = min(max(x0, 0), 62);           // pair (xl, xl+1) stays in row
    float ws0 = 0.f, ws1 = 0.f;
    if (x0 >= 0 && x0 <= 63)         { if (x0 == xl)     ws0 += 1.f - lx; else ws1 += 1.f - lx; }
    if (x0 + 1 >= 0 && x0 + 1 <= 63) { if (x0 + 1 == xl) ws0 += lx;       else ws1 += lx; }
    float wy0 = 1.f - ly, wy1 = ly;
    int oA = 0, oB = 0;
    if (y0 >= 0 && y0 < 64) oA = (y0 << 6) + xl; else wy0 = 0.f;
    if (y0 + 1 >= 0 && y0 + 1 < 64) oB = ((y0 + 1) << 6) + xl; else wy1 = 0.f;
    pPk[idx] = (u32)oA | ((u32)oB << 16);
    pW01[idx] = __floats2half2_rn(wy0 * ws0 * mval, wy0 * ws1 * mval);
    pW23[idx] = __floats2half2_rn(wy1 * ws0 * mval, wy1 * ws1 * mval);
  }
  __syncthreads();

  const char* Db = (const char*)Dc + (size_t)b * 2097152;  // NHWC plane of batch b
  const int wv  = tid >> 6, lane = tid & 63;
  const int wm  = wv & 3,  wn   = wv >> 2;
  const int lr  = lane & 15, lg = lane >> 4;

  uint4 gA0[2], gA1[2], gB0[2], gB1[2];   // corner gathers (coalesced 128B map)
  f32x4 acc[4][4] = {};

  auto issueG = [&](int s) {              // corner loads for step s
    int cblk = s / 9;
    int k = s - cblk * 9;
    u32 cb2 = (u32)(cblk << 7);
#pragma unroll
    for (int u = 0; u < 2; ++u) {
      int tup = (u << 9) + tid;
      int nl2 = tup >> 3, c8 = tup & 7;   // 8 lanes share one n -> 128B segments
      u32 pk = pPk[(k << 7) + nl2];
      u32 ba = (pk & 0xffffu) * 512u + cb2 + (u32)(c8 << 4);
      u32 bb = (pk >> 16) * 512u + cb2 + (u32)(c8 << 4);
      gA0[u] = *(const uint4*)(Db + ba);          // (y0, xl)
      gA1[u] = *(const uint4*)(Db + ba + 512);    // (y0, xl+1)
      gB0[u] = *(const uint4*)(Db + bb);          // (y1, xl)
      gB1[u] = *(const uint4*)(Db + bb + 512);    // (y1, xl+1)
    }
  };

  auto commitG = [&](int s, u16* ctb) {   // blend + swizzled LDS writes
    int k = s - (s / 9) * 9;
#pragma unroll
    for (int u = 0; u < 2; ++u) {
      int tup = (u << 9) + tid;
      int nl2 = tup >> 3, c8 = tup & 7;
      int pi = (k << 7) + nl2;
      __half2 h01 = pW01[pi], h23 = pW23[pi];
      float s0 = __half2float(h01.x), s1 = __half2float(h01.y);
      float s2 = __half2float(h23.x), s3 = __half2float(h23.y);
      u32 o4[4];
      const u32* a0p = (const u32*)&gA0[u];
      const u32* a1p = (const u32*)&gA1[u];
      const u32* b0p = (const u32*)&gB0[u];
      const u32* b1p = (const u32*)&gB1[u];
#pragma unroll
      for (int j = 0; j < 4; ++j) {
        u32 a0 = a0p[j], a1 = a1p[j], b0 = b0p[j], b1 = b1p[j];
        float vlo = s0 * lo16(a0) + s1 * lo16(a1) + s2 * lo16(b0) + s3 * lo16(b1);
        float vhi = s0 * hi16(a0) + s1 * hi16(a1) + s2 * hi16(b0) + s3 * hi16(b1);
        o4[j] = pk2(vlo, vhi);
      }
      int byteoff = nl2 * 128 + ((c8 ^ (nl2 & 7)) << 4);
      *(uint4*)((char*)ctb + byteoff) = make_uint4(o4[0], o4[1], o4[2], o4[3]);
    }
  };

  // ---------- main K loop (ct double-buffered, A direct from global) ----------
  issueG(0);
  commitG(0, ct[0]);
  __syncthreads();
  int cur = 0;
  for (int s = 0; s < NSTEP; ++s) {
    int nx = cur ^ 1;
    const char* slab = (const char*)Wp + (size_t)s * 32768;
    // A-fragment loads first: MFMA's vmcnt wait then covers ONLY these,
    // leaving the 16 next-step gathers (issued below) in flight under MFMA.
    uint4 af[2][4];
#pragma unroll
    for (int kh = 0; kh < 2; ++kh)
#pragma unroll
      for (int fm = 0; fm < 4; ++fm) {
        int o = (wm << 6) + (fm << 4) + lr;
        af[kh][fm] = *(const uint4*)(slab + o * 128 + (kh << 6) + (lg << 4));
      }
    if (s + 1 < NSTEP) issueG(s + 1);     // gathers in flight during MFMA
    const u16* ctb = ct[cur];
#pragma unroll
    for (int kh = 0; kh < 2; ++kh) {
      int c16 = (kh << 2) + lg;
      bf16x8 bfr[4];
#pragma unroll
      for (int fn = 0; fn < 4; ++fn) {
        int nrow = (wn << 6) + (fn << 4) + lr;
        bfr[fn] = *(const bf16x8*)((const char*)ctb + nrow * 128 + ((c16 ^ (nrow & 7)) << 4));
      }
#pragma unroll
      for (int fm = 0; fm < 4; ++fm) {
        bf16x8 a8 = *(const bf16x8*)&af[kh][fm];
#pragma unroll
        for (int fn = 0; fn < 4; ++fn)
          acc[fm][fn] = __builtin_amdgcn_mfma_f32_16x16x32_bf16(a8, bfr[fn], acc[fm][fn], 0, 0, 0);
      }
    }
    if (s + 1 < NSTEP) commitG(s + 1, ct[nx]);
    __syncthreads();
    cur = nx;
  }

  // ---------- epilogue ----------
#pragma unroll
  for (int fm = 0; fm < 4; ++fm) {
    int mb = (wm << 6) + (fm << 4) + (lg << 2);
#pragma unroll
    for (int r = 0; r < 4; ++r) {
      int m = mb + r;
      float bv = bias[m];
      int obase = (((b << 8) + m) << 12) + n0 + (wn << 6) + lr;
#pragma unroll
      for (int fn = 0; fn < 4; ++fn)
        out[obase + (fn << 4)] = acc[fm][fn][r] + bv;
    }
  }
}

extern "C" void kernel_launch(void* const* d_in, const int* in_sizes, int n_in,
                              void* d_out, int out_size, void* d_ws, size_t ws_size,
                              hipStream_t stream) {
  const float* inp  = (const float*)d_in[0];
  const float* off  = (const float*)d_in[1];
  const float* msk  = (const float*)d_in[2];
  const float* wgt  = (const float*)d_in[3];
  const float* bias = (const float*)d_in[4];
  float* out = (float*)d_out;

  u16* Dc = (u16*)d_ws;                                    // 16,777,216 B
  u16* Wp = (u16*)((char*)d_ws + (size_t)16777216);        //  1,179,648 B

  prep_all<<<512 + 2304, 256, 0, stream>>>(inp, wgt, Dc, Wp);
  dcn_main<<<256, 512, 0, stream>>>(Dc, Wp, off, msk, bias, out);
}